// Round 1
// baseline (114.385 us; speedup 1.0000x reference)
//
#include <hip/hip_runtime.h>
#include <math.h>

// Problem constants (fixed by setup_inputs)
#define B_TOTAL 131072
#define K_COMP  64
#define D_DIM   8
#define NC      36
#define CPK     48   // coeff floats per component: 28 S + 8 r + 8 mu + 1 const + 3 pad

// norm_const = -0.5 * D * log(2*pi) = -4 * 1.8378770664093453
#define NORM_CONST (-7.3515082656373815f)

// ---------------------------------------------------------------------------
// Precompute per-component coefficients into d_ws:
//   layout per k (CPK=48 floats):
//   [0..27]  S_ij = L_ij / L_ii   for i=1..7, j<i  (index i*(i-1)/2 + j)
//   [28..35] r_i  = 1 / L_ii
//   [36..43] mu_k[0..7]
//   [44]     const_k = NORM_CONST - sum_i log(L_ii)
// ---------------------------------------------------------------------------
__global__ void mdn_precompute(const float* __restrict__ mu,
                               const float* __restrict__ Lc,
                               float* __restrict__ coeff) {
    int k = threadIdx.x;
    if (k >= K_COMP) return;
    const float* Lk = Lc + k * NC;

    float Lf[D_DIM][D_DIM];
    float r[D_DIM];
    float logdet = 0.0f;
    int idx = 0;
#pragma unroll
    for (int i = 0; i < D_DIM; i++) {
#pragma unroll
        for (int j = 0; j <= i; j++) {
            float v = Lk[idx++];
            if (j == i) {
                r[i] = 1.0f / v;
                logdet += logf(v);
            } else {
                Lf[i][j] = v;
            }
        }
    }

    float* out = coeff + k * CPK;
    int s = 0;
#pragma unroll
    for (int i = 1; i < D_DIM; i++) {
#pragma unroll
        for (int j = 0; j < i; j++) {
            out[s++] = r[i] * Lf[i][j];   // 28 entries
        }
    }
#pragma unroll
    for (int i = 0; i < D_DIM; i++) out[28 + i] = r[i];
#pragma unroll
    for (int i = 0; i < D_DIM; i++) out[36 + i] = mu[k * D_DIM + i];
    out[44] = NORM_CONST - logdet;
}

// ---------------------------------------------------------------------------
// Main kernel: one thread per batch row b.
//   - target row loaded as 2x float4
//   - pi row loaded as float4 per 4 components
//   - coefficient loads are wave-uniform (address depends only on k)
//   - branchless online logsumexp over K=64
//   - wave shuffle + LDS block reduction, one atomicAdd per block
// ---------------------------------------------------------------------------
__global__ __launch_bounds__(256) void mdn_main(const float* __restrict__ pi,
                                                const float* __restrict__ coeff,
                                                const float* __restrict__ target,
                                                float* __restrict__ out) {
    const int b = blockIdx.x * 256 + threadIdx.x;

    // load target row (32B, aligned)
    const float4* tp = (const float4*)(target + (size_t)b * D_DIM);
    float4 t0 = tp[0];
    float4 t1 = tp[1];
    float t[D_DIM] = {t0.x, t0.y, t0.z, t0.w, t1.x, t1.y, t1.z, t1.w};

    const float* pib = pi + (size_t)b * K_COMP;

    float m = -INFINITY;
    float s = 0.0f;

    for (int k4 = 0; k4 < K_COMP / 4; k4++) {
        float4 p4 = *(const float4*)(pib + 4 * k4);
        float pv[4] = {p4.x, p4.y, p4.z, p4.w};
#pragma unroll
        for (int kk = 0; kk < 4; kk++) {
            const int k = 4 * k4 + kk;
            const float* c = coeff + k * CPK;

            float d[D_DIM];
#pragma unroll
            for (int i = 0; i < D_DIM; i++) d[i] = t[i] - c[36 + i];

            // forward substitution: z_i = r_i*d_i - sum_{j<i} S_ij * z_j
            float z[D_DIM];
            z[0] = d[0] * c[28];
#pragma unroll
            for (int i = 1; i < D_DIM; i++) {
                float acc = d[i] * c[28 + i];
                const int sbase = i * (i - 1) / 2;
#pragma unroll
                for (int j = 0; j < i; j++) {
                    acc = fmaf(-c[sbase + j], z[j], acc);
                }
                z[i] = acc;
            }

            float M = 0.0f;
#pragma unroll
            for (int i = 0; i < D_DIM; i++) M = fmaf(z[i], z[i], M);

            float w = fmaf(-0.5f, M, c[44]) + __logf(pv[kk] + 1e-10f);

            // branchless online logsumexp
            float nm = fmaxf(m, w);
            s = s * __expf(m - nm) + __expf(w - nm);
            m = nm;
        }
    }

    float lse = m + __logf(s);

    // wave reduction (64 lanes)
#pragma unroll
    for (int off = 32; off > 0; off >>= 1) lse += __shfl_down(lse, off);

    __shared__ float wsum[4];
    const int lane = threadIdx.x & 63;
    const int wid = threadIdx.x >> 6;
    if (lane == 0) wsum[wid] = lse;
    __syncthreads();
    if (threadIdx.x == 0) {
        float bs = wsum[0] + wsum[1] + wsum[2] + wsum[3];
        atomicAdd(out, bs * (-1.0f / (float)B_TOTAL));
    }
}

extern "C" void kernel_launch(void* const* d_in, const int* in_sizes, int n_in,
                              void* d_out, int out_size, void* d_ws, size_t ws_size,
                              hipStream_t stream) {
    const float* pi  = (const float*)d_in[0];
    const float* mu  = (const float*)d_in[1];
    const float* Lc  = (const float*)d_in[2];
    const float* tgt = (const float*)d_in[3];
    float* out   = (float*)d_out;
    float* coeff = (float*)d_ws;   // 64 * 48 * 4 = 12,288 bytes

    hipMemsetAsync(d_out, 0, sizeof(float), stream);
    mdn_precompute<<<1, 64, 0, stream>>>(mu, Lc, coeff);
    mdn_main<<<B_TOTAL / 256, 256, 0, stream>>>(pi, coeff, tgt, out);
}